// Round 1
// 403.214 us; speedup vs baseline: 1.0272x; 1.0272x over previous
//
#include <hip/hip_runtime.h>
#include <cstdint>
#include <cstddef>

// TreeLSTM (T=256,B=512,IN=128,M=256,BF=2) — level-scheduled wavefront, R6:
//  - level_mfma: 3-buffer rotation, 2-deep prefetch, counted s_waitcnt vmcnt(5)
//    + raw s_barrier per chunk (T3/T4). Uniform 5 vmem ops per stage via a
//    zero-page in ws (replaces divergent ds_write zero-fill), so the vmcnt
//    immediates are exact. csh2 removed (per-lane direct int2 child loads).
//  - conv_all additionally zeroes the 1 KiB zero page (one extra block).
//  - prep_sim / prep_levels / root_gather identical to R5 (verified).

#define TT 256
#define BB 512
#define INN 128
#define MM 256
#define BFN 2
#define NLEVEL_LAUNCH 4
#define SL (TT + BFN)
#define KC 32

typedef __attribute__((ext_vector_type(8))) short bf16x8;
typedef __attribute__((ext_vector_type(8))) unsigned short ushort8;
typedef __attribute__((ext_vector_type(16))) float f32x16;

__device__ __forceinline__ unsigned short f2bf(float f) {
  unsigned u = __float_as_uint(f);
  unsigned r = u + 0x7fffu + ((u >> 16) & 1u);  // RTN-even
  return (unsigned short)(r >> 16);
}

__device__ __forceinline__ float sigm_fast(float x) {
  return __builtin_amdgcn_rcpf(1.0f + __expf(-x));
}
__device__ __forceinline__ float tanh_fast(float x) {
  // tanh(x) = 1 - 2/(e^{2x}+1); inf-safe for large |x|
  return 1.0f - 2.0f * __builtin_amdgcn_rcpf(1.0f + __expf(2.0f * x));
}

__device__ __forceinline__ void async16(unsigned short* lds,
                                        const unsigned short* g) {
  __builtin_amdgcn_global_load_lds(
      (const __attribute__((address_space(1))) unsigned int*)g,
      (__attribute__((address_space(3))) unsigned int*)lds, 16, 0, 0);
}

// ---------------------------------------------------------------------------
// Stack simulation (semantics verified R1-R5).
// ---------------------------------------------------------------------------
__global__ __launch_bounds__(32) void prep_sim(const int* __restrict__ ar,
                                               int* __restrict__ cidx,
                                               int* __restrict__ root) {
  __shared__ int st[32][SL];
  const int tid = threadIdx.x;
  const int b = blockIdx.x * 32 + tid;
  int* s = st[tid];
  for (int i = 0; i < SL; i++) s[i] = 0;
  int sp = BFN - 1;  // 1, kept in [0, SL)

  auto step = [&](int t, int a) {
    int2 cv;
    {
      int pos = sp;
      const int idx = s[pos];
      cv.x = (a > 0 && idx < t) ? idx : -1;
    }
    {
      int pos = sp - 1;
      if (pos < 0) pos += SL;
      const int idx = s[pos];
      cv.y = (a > 1 && idx < t) ? idx : -1;
    }
    *(int2*)&cidx[((size_t)t * BB + b) * BFN] = cv;
    const int aa = a < 0 ? -a : a;
    sp = sp + 1 - aa;
    if (sp < 0) sp += SL;
    if (sp >= SL) sp -= SL;
    if (a != -1) s[sp] = t;
  };

  int a0 = ar[b], a1 = ar[BB + b], a2 = ar[2 * BB + b], a3 = ar[3 * BB + b];
  for (int t = 0; t < TT; t += 4) {
    int n0 = 0, n1 = 0, n2 = 0, n3 = 0;
    if (t + 4 < TT) {
      n0 = ar[(size_t)(t + 4) * BB + b];
      n1 = ar[(size_t)(t + 5) * BB + b];
      n2 = ar[(size_t)(t + 6) * BB + b];
      n3 = ar[(size_t)(t + 7) * BB + b];
    }
    step(t, a0);
    step(t + 1, a1);
    step(t + 2, a2);
    step(t + 3, a3);
    a0 = n0; a1 = n1; a2 = n2; a3 = n3;
  }
  root[b] = s[sp];
}

// ---------------------------------------------------------------------------
// Level assignment — parallel (unchanged from R5).
// ---------------------------------------------------------------------------
__global__ __launch_bounds__(256) void prep_levels(const int* __restrict__ cidx,
                                                   int* __restrict__ order,
                                                   int* __restrict__ levelStart) {
  __shared__ int c0s[TT], c1s[TT], lv[TT];
  const int tid = threadIdx.x;
  if (tid < TT) {
    c0s[tid] = cidx[((size_t)tid * BB) * BFN + 0];
    c1s[tid] = cidx[((size_t)tid * BB) * BFN + 1];
    lv[tid] = 0;
  }
  __syncthreads();
  for (int it = 0; it < NLEVEL_LAUNCH - 1; it++) {
    int nl = 0;
    if (tid < TT) {
      const int c0 = c0s[tid], c1 = c1s[tid];
      if (c0 >= 0) nl = lv[c0] + 1;
      if (c1 >= 0) {
        const int v = lv[c1] + 1;
        if (v > nl) nl = v;
      }
    }
    __syncthreads();
    if (tid < TT) lv[tid] = nl;
    __syncthreads();
  }
  if (tid < TT) {
    const int l = lv[tid];
    int pos = 0;
    for (int j = 0; j < TT; j++) {
      const int lj = lv[j];  // same j across lanes -> LDS broadcast
      pos += (lj < l || (lj == l && j < tid)) ? 1 : 0;
    }
    order[pos] = tid;
  }
  if (tid <= NLEVEL_LAUNCH) {
    int c = 0;
    for (int j = 0; j < TT; j++) c += (lv[j] < tid) ? 1 : 0;
    levelStart[tid] = c;
  }
}

// ---------------------------------------------------------------------------
// Fused weight + x conversion fp32 -> bf16 (one launch) + zero-page write.
// threads [0,61440): weights; [61440, 61440+2097152): x;
// [2158592, 2158592+64): zero page (1 KiB).
// ---------------------------------------------------------------------------
__global__ __launch_bounds__(256) void conv_all(
    const float* __restrict__ x, const float* __restrict__ Wi,
    const float* __restrict__ Wo, const float* __restrict__ Wu,
    const float* __restrict__ Ui, const float* __restrict__ Uo,
    const float* __restrict__ Uu, unsigned short* __restrict__ wb,
    unsigned short* __restrict__ xb, unsigned short* __restrict__ zb) {
  const int gid = blockIdx.x * 256 + threadIdx.x;  // grid = 8433 blocks
  if (gid >= 2158592) {
    if (gid < 2158592 + 64) {
      const ushort8 z = {0, 0, 0, 0, 0, 0, 0, 0};
      *(ushort8*)(zb + (size_t)(gid - 2158592) * 8) = z;
    }
    return;
  }
  const float* src;
  unsigned short* dst;
  size_t off;
  if (gid < 61440) {
    const int g8 = gid * 8;
    dst = wb + g8;
    if (g8 < 98304) {
      const int seg = g8 >> 15;
      off = g8 & 32767;
      src = (seg == 0) ? Wi : (seg == 1) ? Wo : Wu;
    } else {
      const int g2 = g8 - 98304;
      const int seg = g2 >> 17;
      off = g2 & 131071;
      src = (seg == 0) ? Ui : (seg == 1) ? Uo : Uu;
    }
  } else {
    off = ((size_t)(gid - 61440)) * 8;
    src = x;
    dst = xb + off;
  }
  const float4 v0 = *(const float4*)(src + off);
  const float4 v1 = *(const float4*)(src + off + 4);
  ushort8 o;
  o[0] = f2bf(v0.x); o[1] = f2bf(v0.y); o[2] = f2bf(v0.z); o[3] = f2bf(v0.w);
  o[4] = f2bf(v1.x); o[5] = f2bf(v1.y); o[6] = f2bf(v1.z); o[7] = f2bf(v1.w);
  *(ushort8*)dst = o;
}

// ---------------------------------------------------------------------------
// Fused per-level MFMA GEMM + activation.
// R6: 3-buffer rotation, 2-deep prefetch, counted vmcnt, 1 raw barrier/chunk.
// Every stage issues EXACTLY 5 global_load_lds (zero-page for c<0 children),
// so "s_waitcnt vmcnt(5)" leaves precisely the newest stage in flight.
// ---------------------------------------------------------------------------
__global__ __launch_bounds__(256, 2) void level_mfma(
    const unsigned short* __restrict__ xb, float* __restrict__ hf,
    unsigned short* __restrict__ hb, const float* __restrict__ bi,
    const float* __restrict__ bo, const float* __restrict__ bu,
    const unsigned short* __restrict__ wb, const int* __restrict__ cidx,
    const int* __restrict__ order, const int* __restrict__ levelStart,
    const unsigned short* __restrict__ zb, const int level) {
  const int s0 = levelStart[level];
  const int nt = levelStart[level + 1] - s0;
  if (nt <= 0) return;
  const int nTiles = nt * 16;
  const int xchunk = (nTiles + 7) >> 3;

  __shared__ __align__(16) unsigned short AW[3 * 10240];  // 60 KiB, 3 bufs
  __shared__ int flagSh;

  const int tid = threadIdx.x;
  const int lane = tid & 63;
  const int w = tid >> 6;
  const int ln32 = lane & 31;
  const int lh = lane >> 5;
  const int bw = w & 1;
  const int mw = w >> 1;
  const int lrow = lane >> 2;
  const int skq = (lane & 3) ^ (lrow & 3);  // swizzled source granule

  for (int it = blockIdx.x; it < (xchunk << 3); it += gridDim.x) {
    const int tile = (it & 7) * xchunk + (it >> 3);  // XCD-chunked order
    if (tile >= nTiles) continue;
    const int t = order[s0 + (tile >> 4)];
    const int sub = tile & 15;
    const int b0 = (sub >> 2) << 7;
    const int m0 = (sub & 3) << 6;

    // ---- tile prologue -------------------------------------------------
    if (tid == 0) flagSh = 0;
    __syncthreads();  // prev tile done with LDS; flag-zero visible

    // per-lane child indices + biases; issue BEFORE stages so compiler
    // waits for them without draining the staged DMAs.
    const int rA0 = w * 16 + lrow;
    const int rA1 = rA0 + 64;
    const int2 ca = *(const int2*)&cidx[((size_t)t * BB + b0 + rA0) * BFN];
    const int2 cb = *(const int2*)&cidx[((size_t)t * BB + b0 + rA1) * BFN];
    const int cA0 = ca.x, cB0 = ca.y, cA1 = cb.x, cB1 = cb.y;
    const int mcol = m0 + mw * 32 + ln32;
    const float vi = bi[mcol], vo = bo[mcol], vu = bu[mcol];
    __builtin_amdgcn_sched_barrier(0);

    int pf = 0;  // finalized after the prologue barrier

    auto stage_chunk = [&](int ci, unsigned short* buf) {
      int seg, k0;
      if (ci < 4) {
        seg = 0;
        k0 = ci * KC;
      } else {
        const int j = ci - 4;
        if ((pf & 1) && j < 8) {
          seg = 1;
          k0 = j * KC;
        } else {
          seg = 2;
          k0 = ((pf & 1) ? j - 8 : j) * KC;
        }
      }
      if (seg == 0) {
#pragma unroll
        for (int u = 0; u < 2; u++) {
          const int j = w + u * 4;
          const int row = j * 16 + lrow;
          async16(buf + j * 512,
                  xb + (((size_t)t * BB + b0 + row) << 7) + k0 + skq * 8);
        }
      } else {
#pragma unroll
        for (int u = 0; u < 2; u++) {
          const int j = w + u * 4;
          const int c = (seg == 1) ? (u ? cA1 : cA0) : (u ? cB1 : cB0);
          const int row = j * 16 + lrow;
          const unsigned short* src =
              (c >= 0)
                  ? hb + (((size_t)c * BB + b0 + row) << 8) + k0 + skq * 8
                  : zb + lane * 8;  // zero page: uniform vmem count
          async16(buf + j * 512, src);
        }
      }
      {
        const unsigned short* wB = wb + 98304 + (size_t)(seg - 1) * 65536;
#pragma unroll
        for (int u = 0; u < 3; u++) {
          const int jw = w + u * 4;
          const int roww = jw * 16 + lrow;
          const int g3 = roww >> 6;
          const int m = m0 + (roww & 63);
          const unsigned short* base =
              (seg == 0) ? (wb + g3 * 32768 + (size_t)m * INN)
                         : (wB + (size_t)g3 * 131072 + (size_t)m * MM);
          async16(buf + 4096 + jw * 512, base + k0 + skq * 8);
        }
      }
    };

    // prologue: stage chunks 0,1 (always x-segment; pf not needed)
    stage_chunk(0, AW);
    stage_chunk(1, AW + 10240);

    int fl = 0;
    if (__any(cA0 >= 0 || cA1 >= 0)) fl |= 1;
    if (__any(cB0 >= 0 || cB1 >= 0)) fl |= 2;
    if (lane == 0 && fl) atomicOr(&flagSh, fl);
    asm volatile("s_waitcnt lgkmcnt(0)" ::: "memory");
    __builtin_amdgcn_s_barrier();  // ORs visible; DMAs stay in flight
    __builtin_amdgcn_sched_barrier(0);
    pf = flagSh;
    const int nCh = 4 + ((pf & 1) ? 8 : 0) + ((pf & 2) ? 8 : 0);

    // ---- acc init ------------------------------------------------------
    f32x16 aI[2], aO[2], aU[2];
#pragma unroll
    for (int bt = 0; bt < 2; bt++)
#pragma unroll
      for (int r = 0; r < 16; r++) {
        aI[bt][r] = vi;
        aO[bt][r] = vo;
        aU[bt][r] = vu;
      }

    // ---- main chunk loop: 3-buf rotation, 2-deep, counted vmcnt --------
    int cur = 0, nxt2 = 2;
    for (int i = 0; i < nCh; i++) {
      // drain stage(i) only; stage(i+1) (5 newest vmem ops) stays in flight
      if (i + 1 < nCh)
        asm volatile("s_waitcnt vmcnt(5) lgkmcnt(0)" ::: "memory");
      else
        asm volatile("s_waitcnt vmcnt(0) lgkmcnt(0)" ::: "memory");
      __builtin_amdgcn_s_barrier();
      __builtin_amdgcn_sched_barrier(0);  // nothing crosses above barrier

      if (i + 2 < nCh) stage_chunk(i + 2, AW + nxt2 * 10240);

      // MFMA over buffer cur
      {
        const unsigned short* buf = AW + cur * 10240;
        const int r0 = bw * 64 + ln32;
        const int r1 = r0 + 32;
        const int rw = mw * 32 + ln32;
        const int sw3 = ln32 & 3;
#pragma unroll
        for (int ks = 0; ks < 2; ks++) {
          const int kq = ks * 2 + lh;
          const int sa = (kq ^ sw3) * 8;
          const bf16x8 a0 = *(const bf16x8*)(buf + r0 * 32 + sa);
          const bf16x8 a1 = *(const bf16x8*)(buf + r1 * 32 + sa);
          const bf16x8 bI = *(const bf16x8*)(buf + 4096 + rw * 32 + sa);
          const bf16x8 bO = *(const bf16x8*)(buf + 4096 + (64 + rw) * 32 + sa);
          const bf16x8 bU = *(const bf16x8*)(buf + 4096 + (128 + rw) * 32 + sa);
          aI[0] = __builtin_amdgcn_mfma_f32_32x32x16_bf16(a0, bI, aI[0], 0, 0, 0);
          aO[0] = __builtin_amdgcn_mfma_f32_32x32x16_bf16(a0, bO, aO[0], 0, 0, 0);
          aU[0] = __builtin_amdgcn_mfma_f32_32x32x16_bf16(a0, bU, aU[0], 0, 0, 0);
          aI[1] = __builtin_amdgcn_mfma_f32_32x32x16_bf16(a1, bI, aI[1], 0, 0, 0);
          aO[1] = __builtin_amdgcn_mfma_f32_32x32x16_bf16(a1, bO, aO[1], 0, 0, 0);
          aU[1] = __builtin_amdgcn_mfma_f32_32x32x16_bf16(a1, bU, aU[1], 0, 0, 0);
        }
      }
      cur = (cur == 2) ? 0 : cur + 1;
      nxt2 = (nxt2 == 2) ? 0 : nxt2 + 1;
    }

    // ---- epilogue: C/D layout col=lane&31, row=(r&3)+8*(r>>2)+4*lh -----
#pragma unroll
    for (int bt = 0; bt < 2; bt++) {
#pragma unroll
      for (int r = 0; r < 16; r++) {
        const int brow = b0 + bw * 64 + bt * 32 + (r & 3) + 8 * (r >> 2) + 4 * lh;
        const float gi = aI[bt][r];
        const float go = aO[bt][r];
        const float gu = aU[bt][r];
        const float c = sigm_fast(gi) * tanh_fast(gu);
        const float hv = sigm_fast(go) * tanh_fast(c);
        hf[((size_t)t * BB + brow) * MM + mcol] = hv;
        hb[(((size_t)t * BB + brow) << 8) + mcol] = f2bf(hv);
      }
    }
  }
}

// ---------------------------------------------------------------------------
// Root gather: out[b][m] = h[root[b]][b][m]
// ---------------------------------------------------------------------------
__global__ __launch_bounds__(256) void root_gather(const float* __restrict__ h,
                                                   const int* __restrict__ root,
                                                   float* __restrict__ out) {
  const int idx = blockIdx.x * 256 + threadIdx.x;
  const int b = idx >> 8;
  const int m = idx & 255;
  out[idx] = h[((size_t)root[b] * BB + b) * MM + m];
}

extern "C" void kernel_launch(void* const* d_in, const int* in_sizes, int n_in,
                              void* d_out, int out_size, void* d_ws,
                              size_t ws_size, hipStream_t stream) {
  const float* x = (const float*)d_in[0];
  const int* ar = (const int*)d_in[1];
  const float* Wi = (const float*)d_in[2];
  const float* bi = (const float*)d_in[3];
  const float* Wo = (const float*)d_in[4];
  const float* bo = (const float*)d_in[5];
  const float* Wu = (const float*)d_in[6];
  const float* bu = (const float*)d_in[7];
  // d_in[8]=Wf, d_in[9]=bf_b, d_in[13]=Uf: dead in the reference (fc_sum bug)
  const float* Ui = (const float*)d_in[10];
  const float* Uo = (const float*)d_in[11];
  const float* Uu = (const float*)d_in[12];

  float* out = (float*)d_out;
  float* hf = out + (size_t)BB * MM;  // memory[:, :, :M] region, [T][B][M]

  // ws layout identical to R3/R5 + 1 KiB zero page appended after hb:
  int* cidx = (int*)d_ws;                    // 262144 ints
  int* root = cidx + (size_t)TT * BB * BFN;  // 512
  int* order = root + BB;                    // 256
  int* levelStart = order + TT;              // 8
  unsigned short* wb = (unsigned short*)((char*)d_ws + 1051712);   // 491520 sh
  unsigned short* xb = (unsigned short*)((char*)d_ws + 2034752);   // 16.7M sh
  unsigned short* hb = (unsigned short*)((char*)d_ws + 35589184);  // 33.5M sh
  unsigned short* zb = (unsigned short*)((char*)d_ws + 102698048); // 512 sh

  prep_sim<<<BB / 32, 32, 0, stream>>>(ar, cidx, root);
  prep_levels<<<1, 256, 0, stream>>>(cidx, order, levelStart);
  conv_all<<<8433, 256, 0, stream>>>(x, Wi, Wo, Wu, Ui, Uo, Uu, wb, xb, zb);
  for (int lev = 0; lev < NLEVEL_LAUNCH; lev++) {
    level_mfma<<<4096, 256, 0, stream>>>(xb, hf, hb, bi, bo, bu, wb, cidx,
                                         order, levelStart, zb, lev);
  }
  root_gather<<<(BB * MM) / 256, 256, 0, stream>>>(hf, root, out);
}

// Round 2
// 402.473 us; speedup vs baseline: 1.0291x; 1.0018x over previous
//
#include <hip/hip_runtime.h>
#include <cstdint>
#include <cstddef>

// TreeLSTM (T=256,B=512,IN=128,M=256,BF=2) — level-scheduled wavefront, R7:
//  - level_mfma: LDS bank-conflict fix. Old slot map (row-major within each
//    1 KiB DMA block, granule XOR row&3) left rows r,r+4 on identical banks
//    -> 8-way conflict on every ds_read_b128 (SQ_LDS_BANK_CONFLICT=1.3e7).
//    New slot map: slot = (g ^ (row&3))*16 + (row&15)  (granule-major), so
//    bank-group(row,kq) = row mod 8 -> uniform 8 lanes/group (minimum).
//    Store side: linear DMA dest, per-lane SOURCE remap lrow=lane&15,
//    skq=(lane>>4)^(lane&3). Read side: matching inverse (loff()).
//  - 3-buffer rotation + counted vmcnt(5) pipeline kept from R6 (verified).
//  - prep_sim / prep_levels / conv_all / root_gather identical to R6.

#define TT 256
#define BB 512
#define INN 128
#define MM 256
#define BFN 2
#define NLEVEL_LAUNCH 4
#define SL (TT + BFN)
#define KC 32

typedef __attribute__((ext_vector_type(8))) short bf16x8;
typedef __attribute__((ext_vector_type(8))) unsigned short ushort8;
typedef __attribute__((ext_vector_type(16))) float f32x16;

__device__ __forceinline__ unsigned short f2bf(float f) {
  unsigned u = __float_as_uint(f);
  unsigned r = u + 0x7fffu + ((u >> 16) & 1u);  // RTN-even
  return (unsigned short)(r >> 16);
}

__device__ __forceinline__ float sigm_fast(float x) {
  return __builtin_amdgcn_rcpf(1.0f + __expf(-x));
}
__device__ __forceinline__ float tanh_fast(float x) {
  // tanh(x) = 1 - 2/(e^{2x}+1); inf-safe for large |x|
  return 1.0f - 2.0f * __builtin_amdgcn_rcpf(1.0f + __expf(2.0f * x));
}

__device__ __forceinline__ void async16(unsigned short* lds,
                                        const unsigned short* g) {
  __builtin_amdgcn_global_load_lds(
      (const __attribute__((address_space(1))) unsigned int*)g,
      (__attribute__((address_space(3))) unsigned int*)lds, 16, 0, 0);
}

// ---------------------------------------------------------------------------
// Stack simulation (semantics verified R1-R6).
// ---------------------------------------------------------------------------
__global__ __launch_bounds__(32) void prep_sim(const int* __restrict__ ar,
                                               int* __restrict__ cidx,
                                               int* __restrict__ root) {
  __shared__ int st[32][SL];
  const int tid = threadIdx.x;
  const int b = blockIdx.x * 32 + tid;
  int* s = st[tid];
  for (int i = 0; i < SL; i++) s[i] = 0;
  int sp = BFN - 1;  // 1, kept in [0, SL)

  auto step = [&](int t, int a) {
    int2 cv;
    {
      int pos = sp;
      const int idx = s[pos];
      cv.x = (a > 0 && idx < t) ? idx : -1;
    }
    {
      int pos = sp - 1;
      if (pos < 0) pos += SL;
      const int idx = s[pos];
      cv.y = (a > 1 && idx < t) ? idx : -1;
    }
    *(int2*)&cidx[((size_t)t * BB + b) * BFN] = cv;
    const int aa = a < 0 ? -a : a;
    sp = sp + 1 - aa;
    if (sp < 0) sp += SL;
    if (sp >= SL) sp -= SL;
    if (a != -1) s[sp] = t;
  };

  int a0 = ar[b], a1 = ar[BB + b], a2 = ar[2 * BB + b], a3 = ar[3 * BB + b];
  for (int t = 0; t < TT; t += 4) {
    int n0 = 0, n1 = 0, n2 = 0, n3 = 0;
    if (t + 4 < TT) {
      n0 = ar[(size_t)(t + 4) * BB + b];
      n1 = ar[(size_t)(t + 5) * BB + b];
      n2 = ar[(size_t)(t + 6) * BB + b];
      n3 = ar[(size_t)(t + 7) * BB + b];
    }
    step(t, a0);
    step(t + 1, a1);
    step(t + 2, a2);
    step(t + 3, a3);
    a0 = n0; a1 = n1; a2 = n2; a3 = n3;
  }
  root[b] = s[sp];
}

// ---------------------------------------------------------------------------
// Level assignment — parallel (unchanged from R5).
// ---------------------------------------------------------------------------
__global__ __launch_bounds__(256) void prep_levels(const int* __restrict__ cidx,
                                                   int* __restrict__ order,
                                                   int* __restrict__ levelStart) {
  __shared__ int c0s[TT], c1s[TT], lv[TT];
  const int tid = threadIdx.x;
  if (tid < TT) {
    c0s[tid] = cidx[((size_t)tid * BB) * BFN + 0];
    c1s[tid] = cidx[((size_t)tid * BB) * BFN + 1];
    lv[tid] = 0;
  }
  __syncthreads();
  for (int it = 0; it < NLEVEL_LAUNCH - 1; it++) {
    int nl = 0;
    if (tid < TT) {
      const int c0 = c0s[tid], c1 = c1s[tid];
      if (c0 >= 0) nl = lv[c0] + 1;
      if (c1 >= 0) {
        const int v = lv[c1] + 1;
        if (v > nl) nl = v;
      }
    }
    __syncthreads();
    if (tid < TT) lv[tid] = nl;
    __syncthreads();
  }
  if (tid < TT) {
    const int l = lv[tid];
    int pos = 0;
    for (int j = 0; j < TT; j++) {
      const int lj = lv[j];  // same j across lanes -> LDS broadcast
      pos += (lj < l || (lj == l && j < tid)) ? 1 : 0;
    }
    order[pos] = tid;
  }
  if (tid <= NLEVEL_LAUNCH) {
    int c = 0;
    for (int j = 0; j < TT; j++) c += (lv[j] < tid) ? 1 : 0;
    levelStart[tid] = c;
  }
}

// ---------------------------------------------------------------------------
// Fused weight + x conversion fp32 -> bf16 (one launch) + zero-page write.
// ---------------------------------------------------------------------------
__global__ __launch_bounds__(256) void conv_all(
    const float* __restrict__ x, const float* __restrict__ Wi,
    const float* __restrict__ Wo, const float* __restrict__ Wu,
    const float* __restrict__ Ui, const float* __restrict__ Uo,
    const float* __restrict__ Uu, unsigned short* __restrict__ wb,
    unsigned short* __restrict__ xb, unsigned short* __restrict__ zb) {
  const int gid = blockIdx.x * 256 + threadIdx.x;  // grid = 8433 blocks
  if (gid >= 2158592) {
    if (gid < 2158592 + 64) {
      const ushort8 z = {0, 0, 0, 0, 0, 0, 0, 0};
      *(ushort8*)(zb + (size_t)(gid - 2158592) * 8) = z;
    }
    return;
  }
  const float* src;
  unsigned short* dst;
  size_t off;
  if (gid < 61440) {
    const int g8 = gid * 8;
    dst = wb + g8;
    if (g8 < 98304) {
      const int seg = g8 >> 15;
      off = g8 & 32767;
      src = (seg == 0) ? Wi : (seg == 1) ? Wo : Wu;
    } else {
      const int g2 = g8 - 98304;
      const int seg = g2 >> 17;
      off = g2 & 131071;
      src = (seg == 0) ? Ui : (seg == 1) ? Uo : Uu;
    }
  } else {
    off = ((size_t)(gid - 61440)) * 8;
    src = x;
    dst = xb + off;
  }
  const float4 v0 = *(const float4*)(src + off);
  const float4 v1 = *(const float4*)(src + off + 4);
  ushort8 o;
  o[0] = f2bf(v0.x); o[1] = f2bf(v0.y); o[2] = f2bf(v0.z); o[3] = f2bf(v0.w);
  o[4] = f2bf(v1.x); o[5] = f2bf(v1.y); o[6] = f2bf(v1.z); o[7] = f2bf(v1.w);
  *(ushort8*)dst = o;
}

// ---------------------------------------------------------------------------
// Fused per-level MFMA GEMM + activation.
// R7: granule-major LDS slot map (bank-conflict-free ds_read_b128).
// Slot s in each 1 KiB DMA block holds (row = s&15, src granule = (s>>4)^(s&3)).
// Read (row r, k-quad kq) at slot ((kq^(r&3))<<4) | (r&15)  -> bank-group
// = r mod 8, uniform across a 32-row read. 3-buf + vmcnt(5) kept from R6.
// ---------------------------------------------------------------------------
__global__ __launch_bounds__(256, 2) void level_mfma(
    const unsigned short* __restrict__ xb, float* __restrict__ hf,
    unsigned short* __restrict__ hb, const float* __restrict__ bi,
    const float* __restrict__ bo, const float* __restrict__ bu,
    const unsigned short* __restrict__ wb, const int* __restrict__ cidx,
    const int* __restrict__ order, const int* __restrict__ levelStart,
    const unsigned short* __restrict__ zb, const int level) {
  const int s0 = levelStart[level];
  const int nt = levelStart[level + 1] - s0;
  if (nt <= 0) return;
  const int nTiles = nt * 16;
  const int xchunk = (nTiles + 7) >> 3;

  __shared__ __align__(16) unsigned short AW[3 * 10240];  // 60 KiB, 3 bufs
  __shared__ int flagSh;

  const int tid = threadIdx.x;
  const int lane = tid & 63;
  const int w = tid >> 6;
  const int ln32 = lane & 31;
  const int lh = lane >> 5;
  const int bw = w & 1;
  const int mw = w >> 1;
  const int lrow = lane & 15;                 // row within 16-row DMA block
  const int skq = (lane >> 4) ^ (lane & 3);   // source granule for slot(lane)

  // LDS offset (shorts) of (row r, k-quad kq) within an A/B region.
  auto loff = [](int r, int kq) {
    return ((r >> 4) << 9) + (((((kq ^ (r & 3)) << 4) | (r & 15))) << 3);
  };

  for (int it = blockIdx.x; it < (xchunk << 3); it += gridDim.x) {
    const int tile = (it & 7) * xchunk + (it >> 3);  // XCD-chunked order
    if (tile >= nTiles) continue;
    const int t = order[s0 + (tile >> 4)];
    const int sub = tile & 15;
    const int b0 = (sub >> 2) << 7;
    const int m0 = (sub & 3) << 6;

    // ---- tile prologue -------------------------------------------------
    if (tid == 0) flagSh = 0;
    __syncthreads();  // prev tile done with LDS; flag-zero visible

    const int rA0 = w * 16 + lrow;   // row this lane stages for u=0
    const int rA1 = rA0 + 64;        // row for u=1
    const int2 ca = *(const int2*)&cidx[((size_t)t * BB + b0 + rA0) * BFN];
    const int2 cb = *(const int2*)&cidx[((size_t)t * BB + b0 + rA1) * BFN];
    const int cA0 = ca.x, cB0 = ca.y, cA1 = cb.x, cB1 = cb.y;
    const int mcol = m0 + mw * 32 + ln32;
    const float vi = bi[mcol], vo = bo[mcol], vu = bu[mcol];
    __builtin_amdgcn_sched_barrier(0);

    int pf = 0;  // finalized after the prologue barrier

    auto stage_chunk = [&](int ci, unsigned short* buf) {
      int seg, k0;
      if (ci < 4) {
        seg = 0;
        k0 = ci * KC;
      } else {
        const int j = ci - 4;
        if ((pf & 1) && j < 8) {
          seg = 1;
          k0 = j * KC;
        } else {
          seg = 2;
          k0 = ((pf & 1) ? j - 8 : j) * KC;
        }
      }
      if (seg == 0) {
#pragma unroll
        for (int u = 0; u < 2; u++) {
          const int j = w + u * 4;
          const int row = j * 16 + lrow;
          async16(buf + j * 512,
                  xb + (((size_t)t * BB + b0 + row) << 7) + k0 + skq * 8);
        }
      } else {
#pragma unroll
        for (int u = 0; u < 2; u++) {
          const int j = w + u * 4;
          const int c = (seg == 1) ? (u ? cA1 : cA0) : (u ? cB1 : cB0);
          const int row = j * 16 + lrow;
          const unsigned short* src =
              (c >= 0)
                  ? hb + (((size_t)c * BB + b0 + row) << 8) + k0 + skq * 8
                  : zb + lane * 8;  // zero page: uniform vmem count
          async16(buf + j * 512, src);
        }
      }
      {
        const unsigned short* wB = wb + 98304 + (size_t)(seg - 1) * 65536;
#pragma unroll
        for (int u = 0; u < 3; u++) {
          const int jw = w + u * 4;
          const int roww = jw * 16 + lrow;
          const int g3 = roww >> 6;
          const int m = m0 + (roww & 63);
          const unsigned short* base =
              (seg == 0) ? (wb + g3 * 32768 + (size_t)m * INN)
                         : (wB + (size_t)g3 * 131072 + (size_t)m * MM);
          async16(buf + 4096 + jw * 512, base + k0 + skq * 8);
        }
      }
    };

    // prologue: stage chunks 0,1 (always x-segment; pf not needed)
    stage_chunk(0, AW);
    stage_chunk(1, AW + 10240);

    int fl = 0;
    if (__any(cA0 >= 0 || cA1 >= 0)) fl |= 1;
    if (__any(cB0 >= 0 || cB1 >= 0)) fl |= 2;
    if (lane == 0 && fl) atomicOr(&flagSh, fl);
    asm volatile("s_waitcnt lgkmcnt(0)" ::: "memory");
    __builtin_amdgcn_s_barrier();  // ORs visible; DMAs stay in flight
    __builtin_amdgcn_sched_barrier(0);
    pf = flagSh;
    const int nCh = 4 + ((pf & 1) ? 8 : 0) + ((pf & 2) ? 8 : 0);

    // ---- acc init ------------------------------------------------------
    f32x16 aI[2], aO[2], aU[2];
#pragma unroll
    for (int bt = 0; bt < 2; bt++)
#pragma unroll
      for (int r = 0; r < 16; r++) {
        aI[bt][r] = vi;
        aO[bt][r] = vo;
        aU[bt][r] = vu;
      }

    // ---- main chunk loop: 3-buf rotation, 2-deep, counted vmcnt --------
    int cur = 0, nxt2 = 2;
    for (int i = 0; i < nCh; i++) {
      // drain stage(i) only; stage(i+1) (5 newest vmem ops) stays in flight
      if (i + 1 < nCh)
        asm volatile("s_waitcnt vmcnt(5) lgkmcnt(0)" ::: "memory");
      else
        asm volatile("s_waitcnt vmcnt(0) lgkmcnt(0)" ::: "memory");
      __builtin_amdgcn_s_barrier();
      __builtin_amdgcn_sched_barrier(0);  // nothing crosses above barrier

      if (i + 2 < nCh) stage_chunk(i + 2, AW + nxt2 * 10240);

      // MFMA over buffer cur
      {
        const unsigned short* buf = AW + cur * 10240;
        const int r0 = bw * 64 + ln32;
        const int r1 = r0 + 32;
        const int rw = mw * 32 + ln32;
#pragma unroll
        for (int ks = 0; ks < 2; ks++) {
          const int kq = ks * 2 + lh;
          const bf16x8 a0 = *(const bf16x8*)(buf + loff(r0, kq));
          const bf16x8 a1 = *(const bf16x8*)(buf + loff(r1, kq));
          const bf16x8 bI = *(const bf16x8*)(buf + 4096 + loff(rw, kq));
          const bf16x8 bO = *(const bf16x8*)(buf + 4096 + loff(rw + 64, kq));
          const bf16x8 bU = *(const bf16x8*)(buf + 4096 + loff(rw + 128, kq));
          aI[0] = __builtin_amdgcn_mfma_f32_32x32x16_bf16(a0, bI, aI[0], 0, 0, 0);
          aO[0] = __builtin_amdgcn_mfma_f32_32x32x16_bf16(a0, bO, aO[0], 0, 0, 0);
          aU[0] = __builtin_amdgcn_mfma_f32_32x32x16_bf16(a0, bU, aU[0], 0, 0, 0);
          aI[1] = __builtin_amdgcn_mfma_f32_32x32x16_bf16(a1, bI, aI[1], 0, 0, 0);
          aO[1] = __builtin_amdgcn_mfma_f32_32x32x16_bf16(a1, bO, aO[1], 0, 0, 0);
          aU[1] = __builtin_amdgcn_mfma_f32_32x32x16_bf16(a1, bU, aU[1], 0, 0, 0);
        }
      }
      cur = (cur == 2) ? 0 : cur + 1;
      nxt2 = (nxt2 == 2) ? 0 : nxt2 + 1;
    }

    // ---- epilogue: C/D layout col=lane&31, row=(r&3)+8*(r>>2)+4*lh -----
#pragma unroll
    for (int bt = 0; bt < 2; bt++) {
#pragma unroll
      for (int r = 0; r < 16; r++) {
        const int brow = b0 + bw * 64 + bt * 32 + (r & 3) + 8 * (r >> 2) + 4 * lh;
        const float gi = aI[bt][r];
        const float go = aO[bt][r];
        const float gu = aU[bt][r];
        const float c = sigm_fast(gi) * tanh_fast(gu);
        const float hv = sigm_fast(go) * tanh_fast(c);
        hf[((size_t)t * BB + brow) * MM + mcol] = hv;
        hb[(((size_t)t * BB + brow) << 8) + mcol] = f2bf(hv);
      }
    }
  }
}

// ---------------------------------------------------------------------------
// Root gather: out[b][m] = h[root[b]][b][m]
// ---------------------------------------------------------------------------
__global__ __launch_bounds__(256) void root_gather(const float* __restrict__ h,
                                                   const int* __restrict__ root,
                                                   float* __restrict__ out) {
  const int idx = blockIdx.x * 256 + threadIdx.x;
  const int b = idx >> 8;
  const int m = idx & 255;
  out[idx] = h[((size_t)root[b] * BB + b) * MM + m];
}

extern "C" void kernel_launch(void* const* d_in, const int* in_sizes, int n_in,
                              void* d_out, int out_size, void* d_ws,
                              size_t ws_size, hipStream_t stream) {
  const float* x = (const float*)d_in[0];
  const int* ar = (const int*)d_in[1];
  const float* Wi = (const float*)d_in[2];
  const float* bi = (const float*)d_in[3];
  const float* Wo = (const float*)d_in[4];
  const float* bo = (const float*)d_in[5];
  const float* Wu = (const float*)d_in[6];
  const float* bu = (const float*)d_in[7];
  // d_in[8]=Wf, d_in[9]=bf_b, d_in[13]=Uf: dead in the reference (fc_sum bug)
  const float* Ui = (const float*)d_in[10];
  const float* Uo = (const float*)d_in[11];
  const float* Uu = (const float*)d_in[12];

  float* out = (float*)d_out;
  float* hf = out + (size_t)BB * MM;  // memory[:, :, :M] region, [T][B][M]

  // ws layout identical to R6:
  int* cidx = (int*)d_ws;                    // 262144 ints
  int* root = cidx + (size_t)TT * BB * BFN;  // 512
  int* order = root + BB;                    // 256
  int* levelStart = order + TT;              // 8
  unsigned short* wb = (unsigned short*)((char*)d_ws + 1051712);   // 491520 sh
  unsigned short* xb = (unsigned short*)((char*)d_ws + 2034752);   // 16.7M sh
  unsigned short* hb = (unsigned short*)((char*)d_ws + 35589184);  // 33.5M sh
  unsigned short* zb = (unsigned short*)((char*)d_ws + 102698048); // 512 sh

  prep_sim<<<BB / 32, 32, 0, stream>>>(ar, cidx, root);
  prep_levels<<<1, 256, 0, stream>>>(cidx, order, levelStart);
  conv_all<<<8433, 256, 0, stream>>>(x, Wi, Wo, Wu, Ui, Uo, Uu, wb, xb, zb);
  for (int lev = 0; lev < NLEVEL_LAUNCH; lev++) {
    level_mfma<<<4096, 256, 0, stream>>>(xb, hf, hb, bi, bo, bu, wb, cidx,
                                         order, levelStart, zb, lev);
  }
  root_gather<<<(BB * MM) / 256, 256, 0, stream>>>(hf, root, out);
}

// Round 3
// 389.899 us; speedup vs baseline: 1.0623x; 1.0323x over previous
//
#include <hip/hip_runtime.h>
#include <cstdint>
#include <cstddef>

// TreeLSTM (T=256,B=512,IN=128,M=256,BF=2) — level-scheduled wavefront, R8:
//  - level_mfma: pipeline depth 2 -> 3 (4 x 10KiB LDS buffers = exactly 80 KiB
//    -> still 2 blocks/CU). Counted waits: vmcnt(10) steady / 5 / 0 tail.
//    Child-hb gathers are scattered LLC/HBM (~700-900 cyc); depth-2 hid only
//    ~2 chunk-times (~400 cyc) -> chunks were latency-exposed (R7 showed
//    conflicts weren't the bound: swizzle fix moved nothing).
//  - flagSh/atomicOr/extra barrier removed: pf computed per-wave via ballot
//    (each lane checks rows lane and lane+64 -> one wave covers all 128 rows).
//    Removing flagSh is REQUIRED: 4 buffers + flag would round LDS past 80 KiB
//    and halve occupancy.
//  - R7 granule-major LDS swizzle kept (conflict-free ds_read_b128).
//  - prep_sim / prep_levels / conv_all / root_gather identical to R7.

#define TT 256
#define BB 512
#define INN 128
#define MM 256
#define BFN 2
#define NLEVEL_LAUNCH 4
#define SL (TT + BFN)
#define KC 32

typedef __attribute__((ext_vector_type(8))) short bf16x8;
typedef __attribute__((ext_vector_type(8))) unsigned short ushort8;
typedef __attribute__((ext_vector_type(16))) float f32x16;

__device__ __forceinline__ unsigned short f2bf(float f) {
  unsigned u = __float_as_uint(f);
  unsigned r = u + 0x7fffu + ((u >> 16) & 1u);  // RTN-even
  return (unsigned short)(r >> 16);
}

__device__ __forceinline__ float sigm_fast(float x) {
  return __builtin_amdgcn_rcpf(1.0f + __expf(-x));
}
__device__ __forceinline__ float tanh_fast(float x) {
  // tanh(x) = 1 - 2/(e^{2x}+1); inf-safe for large |x|
  return 1.0f - 2.0f * __builtin_amdgcn_rcpf(1.0f + __expf(2.0f * x));
}

__device__ __forceinline__ void async16(unsigned short* lds,
                                        const unsigned short* g) {
  __builtin_amdgcn_global_load_lds(
      (const __attribute__((address_space(1))) unsigned int*)g,
      (__attribute__((address_space(3))) unsigned int*)lds, 16, 0, 0);
}

// ---------------------------------------------------------------------------
// Stack simulation (semantics verified R1-R7).
// ---------------------------------------------------------------------------
__global__ __launch_bounds__(32) void prep_sim(const int* __restrict__ ar,
                                               int* __restrict__ cidx,
                                               int* __restrict__ root) {
  __shared__ int st[32][SL];
  const int tid = threadIdx.x;
  const int b = blockIdx.x * 32 + tid;
  int* s = st[tid];
  for (int i = 0; i < SL; i++) s[i] = 0;
  int sp = BFN - 1;  // 1, kept in [0, SL)

  auto step = [&](int t, int a) {
    int2 cv;
    {
      int pos = sp;
      const int idx = s[pos];
      cv.x = (a > 0 && idx < t) ? idx : -1;
    }
    {
      int pos = sp - 1;
      if (pos < 0) pos += SL;
      const int idx = s[pos];
      cv.y = (a > 1 && idx < t) ? idx : -1;
    }
    *(int2*)&cidx[((size_t)t * BB + b) * BFN] = cv;
    const int aa = a < 0 ? -a : a;
    sp = sp + 1 - aa;
    if (sp < 0) sp += SL;
    if (sp >= SL) sp -= SL;
    if (a != -1) s[sp] = t;
  };

  int a0 = ar[b], a1 = ar[BB + b], a2 = ar[2 * BB + b], a3 = ar[3 * BB + b];
  for (int t = 0; t < TT; t += 4) {
    int n0 = 0, n1 = 0, n2 = 0, n3 = 0;
    if (t + 4 < TT) {
      n0 = ar[(size_t)(t + 4) * BB + b];
      n1 = ar[(size_t)(t + 5) * BB + b];
      n2 = ar[(size_t)(t + 6) * BB + b];
      n3 = ar[(size_t)(t + 7) * BB + b];
    }
    step(t, a0);
    step(t + 1, a1);
    step(t + 2, a2);
    step(t + 3, a3);
    a0 = n0; a1 = n1; a2 = n2; a3 = n3;
  }
  root[b] = s[sp];
}

// ---------------------------------------------------------------------------
// Level assignment — parallel (unchanged from R5).
// ---------------------------------------------------------------------------
__global__ __launch_bounds__(256) void prep_levels(const int* __restrict__ cidx,
                                                   int* __restrict__ order,
                                                   int* __restrict__ levelStart) {
  __shared__ int c0s[TT], c1s[TT], lv[TT];
  const int tid = threadIdx.x;
  if (tid < TT) {
    c0s[tid] = cidx[((size_t)tid * BB) * BFN + 0];
    c1s[tid] = cidx[((size_t)tid * BB) * BFN + 1];
    lv[tid] = 0;
  }
  __syncthreads();
  for (int it = 0; it < NLEVEL_LAUNCH - 1; it++) {
    int nl = 0;
    if (tid < TT) {
      const int c0 = c0s[tid], c1 = c1s[tid];
      if (c0 >= 0) nl = lv[c0] + 1;
      if (c1 >= 0) {
        const int v = lv[c1] + 1;
        if (v > nl) nl = v;
      }
    }
    __syncthreads();
    if (tid < TT) lv[tid] = nl;
    __syncthreads();
  }
  if (tid < TT) {
    const int l = lv[tid];
    int pos = 0;
    for (int j = 0; j < TT; j++) {
      const int lj = lv[j];  // same j across lanes -> LDS broadcast
      pos += (lj < l || (lj == l && j < tid)) ? 1 : 0;
    }
    order[pos] = tid;
  }
  if (tid <= NLEVEL_LAUNCH) {
    int c = 0;
    for (int j = 0; j < TT; j++) c += (lv[j] < tid) ? 1 : 0;
    levelStart[tid] = c;
  }
}

// ---------------------------------------------------------------------------
// Fused weight + x conversion fp32 -> bf16 (one launch) + zero-page write.
// ---------------------------------------------------------------------------
__global__ __launch_bounds__(256) void conv_all(
    const float* __restrict__ x, const float* __restrict__ Wi,
    const float* __restrict__ Wo, const float* __restrict__ Wu,
    const float* __restrict__ Ui, const float* __restrict__ Uo,
    const float* __restrict__ Uu, unsigned short* __restrict__ wb,
    unsigned short* __restrict__ xb, unsigned short* __restrict__ zb) {
  const int gid = blockIdx.x * 256 + threadIdx.x;  // grid = 8433 blocks
  if (gid >= 2158592) {
    if (gid < 2158592 + 64) {
      const ushort8 z = {0, 0, 0, 0, 0, 0, 0, 0};
      *(ushort8*)(zb + (size_t)(gid - 2158592) * 8) = z;
    }
    return;
  }
  const float* src;
  unsigned short* dst;
  size_t off;
  if (gid < 61440) {
    const int g8 = gid * 8;
    dst = wb + g8;
    if (g8 < 98304) {
      const int seg = g8 >> 15;
      off = g8 & 32767;
      src = (seg == 0) ? Wi : (seg == 1) ? Wo : Wu;
    } else {
      const int g2 = g8 - 98304;
      const int seg = g2 >> 17;
      off = g2 & 131071;
      src = (seg == 0) ? Ui : (seg == 1) ? Uo : Uu;
    }
  } else {
    off = ((size_t)(gid - 61440)) * 8;
    src = x;
    dst = xb + off;
  }
  const float4 v0 = *(const float4*)(src + off);
  const float4 v1 = *(const float4*)(src + off + 4);
  ushort8 o;
  o[0] = f2bf(v0.x); o[1] = f2bf(v0.y); o[2] = f2bf(v0.z); o[3] = f2bf(v0.w);
  o[4] = f2bf(v1.x); o[5] = f2bf(v1.y); o[6] = f2bf(v1.z); o[7] = f2bf(v1.w);
  *(ushort8*)dst = o;
}

// ---------------------------------------------------------------------------
// Fused per-level MFMA GEMM + activation.
// R8: 4-buffer rotation, 3-deep prefetch, counted vmcnt(10/5/0),
// ballot-derived pf (no LDS flag), R7 granule-major swizzle.
// Each stage = exactly 5 global_load_lds per wave (zero-page for c<0).
// ---------------------------------------------------------------------------
__global__ __launch_bounds__(256, 2) void level_mfma(
    const unsigned short* __restrict__ xb, float* __restrict__ hf,
    unsigned short* __restrict__ hb, const float* __restrict__ bi,
    const float* __restrict__ bo, const float* __restrict__ bu,
    const unsigned short* __restrict__ wb, const int* __restrict__ cidx,
    const int* __restrict__ order, const int* __restrict__ levelStart,
    const unsigned short* __restrict__ zb, const int level) {
  const int s0 = levelStart[level];
  const int nt = levelStart[level + 1] - s0;
  if (nt <= 0) return;
  const int nTiles = nt * 16;
  const int xchunk = (nTiles + 7) >> 3;

  __shared__ __align__(16) unsigned short AW[4 * 10240];  // exactly 80 KiB

  const int tid = threadIdx.x;
  const int lane = tid & 63;
  const int w = tid >> 6;
  const int ln32 = lane & 31;
  const int lh = lane >> 5;
  const int bw = w & 1;
  const int mw = w >> 1;
  const int lrow = lane & 15;                 // row within 16-row DMA block
  const int skq = (lane >> 4) ^ (lane & 3);   // source granule for slot(lane)

  // LDS offset (shorts) of (row r, k-quad kq) within an A/B region.
  auto loff = [](int r, int kq) {
    return ((r >> 4) << 9) + (((((kq ^ (r & 3)) << 4) | (r & 15))) << 3);
  };

  for (int it = blockIdx.x; it < (xchunk << 3); it += gridDim.x) {
    const int tile = (it & 7) * xchunk + (it >> 3);  // XCD-chunked order
    if (tile >= nTiles) continue;
    const int t = order[s0 + (tile >> 4)];
    const int sub = tile & 15;
    const int b0 = (sub >> 2) << 7;
    const int m0 = (sub & 3) << 6;

    // ---- tile prologue -------------------------------------------------
    __syncthreads();  // prev tile fully done with LDS (no-op on 1st tile)

    // flag loads: rows lane and lane+64 -> one wave covers all 128 rows.
    const int2 fa = *(const int2*)&cidx[((size_t)t * BB + b0 + lane) * BFN];
    const int2 fb =
        *(const int2*)&cidx[((size_t)t * BB + b0 + 64 + lane) * BFN];
    // staging child indices for this lane's DMA rows.
    const int rA0 = w * 16 + lrow;
    const int rA1 = rA0 + 64;
    const int2 ca = *(const int2*)&cidx[((size_t)t * BB + b0 + rA0) * BFN];
    const int2 cb = *(const int2*)&cidx[((size_t)t * BB + b0 + rA1) * BFN];
    const int cA0 = ca.x, cB0 = ca.y, cA1 = cb.x, cB1 = cb.y;
    const int mcol = m0 + mw * 32 + ln32;
    const float vi = bi[mcol], vo = bo[mcol], vu = bu[mcol];

    int pf = 0;  // finalized (via ballot) before first pf-dependent stage

    auto stage_chunk = [&](int ci, unsigned short* buf) {
      int seg, k0;
      if (ci < 4) {
        seg = 0;
        k0 = ci * KC;
      } else {
        const int j = ci - 4;
        if ((pf & 1) && j < 8) {
          seg = 1;
          k0 = j * KC;
        } else {
          seg = 2;
          k0 = ((pf & 1) ? j - 8 : j) * KC;
        }
      }
      if (seg == 0) {
#pragma unroll
        for (int u = 0; u < 2; u++) {
          const int j = w + u * 4;
          const int row = j * 16 + lrow;
          async16(buf + j * 512,
                  xb + (((size_t)t * BB + b0 + row) << 7) + k0 + skq * 8);
        }
      } else {
#pragma unroll
        for (int u = 0; u < 2; u++) {
          const int j = w + u * 4;
          const int c = (seg == 1) ? (u ? cA1 : cA0) : (u ? cB1 : cB0);
          const int row = j * 16 + lrow;
          const unsigned short* src =
              (c >= 0)
                  ? hb + (((size_t)c * BB + b0 + row) << 8) + k0 + skq * 8
                  : zb + lane * 8;  // zero page: uniform vmem count
          async16(buf + j * 512, src);
        }
      }
      {
        const unsigned short* wB = wb + 98304 + (size_t)(seg - 1) * 65536;
#pragma unroll
        for (int u = 0; u < 3; u++) {
          const int jw = w + u * 4;
          const int roww = jw * 16 + lrow;
          const int g3 = roww >> 6;
          const int m = m0 + (roww & 63);
          const unsigned short* base =
              (seg == 0) ? (wb + g3 * 32768 + (size_t)m * INN)
                         : (wB + (size_t)g3 * 131072 + (size_t)m * MM);
          async16(buf + 4096 + jw * 512, base + k0 + skq * 8);
        }
      }
    };

    // prologue: stage chunks 0,1,2 (all x-segment; pf not needed)
    stage_chunk(0, AW);
    stage_chunk(1, AW + 10240);
    stage_chunk(2, AW + 2 * 10240);

    // pf via ballot: identical in every wave (same 128 rows scanned).
    pf = (__any(fa.x >= 0 || fb.x >= 0) ? 1 : 0) |
         (__any(fa.y >= 0 || fb.y >= 0) ? 2 : 0);
    const int nCh = 4 + ((pf & 1) ? 8 : 0) + ((pf & 2) ? 8 : 0);

    // ---- acc init ------------------------------------------------------
    f32x16 aI[2], aO[2], aU[2];
#pragma unroll
    for (int bt = 0; bt < 2; bt++)
#pragma unroll
      for (int r = 0; r < 16; r++) {
        aI[bt][r] = vi;
        aO[bt][r] = vo;
        aU[bt][r] = vu;
      }

    // ---- main chunk loop: 4-buf rotation, 3-deep, counted vmcnt --------
    for (int i = 0; i < nCh; i++) {
      // drain stage(i); stages i+1, i+2 (10 newest vmem ops) stay in flight
      if (i + 2 < nCh)
        asm volatile("s_waitcnt vmcnt(10) lgkmcnt(0)" ::: "memory");
      else if (i + 1 < nCh)
        asm volatile("s_waitcnt vmcnt(5) lgkmcnt(0)" ::: "memory");
      else
        asm volatile("s_waitcnt vmcnt(0) lgkmcnt(0)" ::: "memory");
      __builtin_amdgcn_s_barrier();
      __builtin_amdgcn_sched_barrier(0);  // nothing crosses above barrier

      if (i + 3 < nCh) stage_chunk(i + 3, AW + ((i + 3) & 3) * 10240);

      // MFMA over buffer i&3
      {
        const unsigned short* buf = AW + (i & 3) * 10240;
        const int r0 = bw * 64 + ln32;
        const int r1 = r0 + 32;
        const int rw = mw * 32 + ln32;
#pragma unroll
        for (int ks = 0; ks < 2; ks++) {
          const int kq = ks * 2 + lh;
          const bf16x8 a0 = *(const bf16x8*)(buf + loff(r0, kq));
          const bf16x8 a1 = *(const bf16x8*)(buf + loff(r1, kq));
          const bf16x8 bI = *(const bf16x8*)(buf + 4096 + loff(rw, kq));
          const bf16x8 bO = *(const bf16x8*)(buf + 4096 + loff(rw + 64, kq));
          const bf16x8 bU = *(const bf16x8*)(buf + 4096 + loff(rw + 128, kq));
          aI[0] = __builtin_amdgcn_mfma_f32_32x32x16_bf16(a0, bI, aI[0], 0, 0, 0);
          aO[0] = __builtin_amdgcn_mfma_f32_32x32x16_bf16(a0, bO, aO[0], 0, 0, 0);
          aU[0] = __builtin_amdgcn_mfma_f32_32x32x16_bf16(a0, bU, aU[0], 0, 0, 0);
          aI[1] = __builtin_amdgcn_mfma_f32_32x32x16_bf16(a1, bI, aI[1], 0, 0, 0);
          aO[1] = __builtin_amdgcn_mfma_f32_32x32x16_bf16(a1, bO, aO[1], 0, 0, 0);
          aU[1] = __builtin_amdgcn_mfma_f32_32x32x16_bf16(a1, bU, aU[1], 0, 0, 0);
        }
      }
    }

    // ---- epilogue: C/D layout col=lane&31, row=(r&3)+8*(r>>2)+4*lh -----
#pragma unroll
    for (int bt = 0; bt < 2; bt++) {
#pragma unroll
      for (int r = 0; r < 16; r++) {
        const int brow = b0 + bw * 64 + bt * 32 + (r & 3) + 8 * (r >> 2) + 4 * lh;
        const float gi = aI[bt][r];
        const float go = aO[bt][r];
        const float gu = aU[bt][r];
        const float c = sigm_fast(gi) * tanh_fast(gu);
        const float hv = sigm_fast(go) * tanh_fast(c);
        hf[((size_t)t * BB + brow) * MM + mcol] = hv;
        hb[(((size_t)t * BB + brow) << 8) + mcol] = f2bf(hv);
      }
    }
  }
}

// ---------------------------------------------------------------------------
// Root gather: out[b][m] = h[root[b]][b][m]
// ---------------------------------------------------------------------------
__global__ __launch_bounds__(256) void root_gather(const float* __restrict__ h,
                                                   const int* __restrict__ root,
                                                   float* __restrict__ out) {
  const int idx = blockIdx.x * 256 + threadIdx.x;
  const int b = idx >> 8;
  const int m = idx & 255;
  out[idx] = h[((size_t)root[b] * BB + b) * MM + m];
}

extern "C" void kernel_launch(void* const* d_in, const int* in_sizes, int n_in,
                              void* d_out, int out_size, void* d_ws,
                              size_t ws_size, hipStream_t stream) {
  const float* x = (const float*)d_in[0];
  const int* ar = (const int*)d_in[1];
  const float* Wi = (const float*)d_in[2];
  const float* bi = (const float*)d_in[3];
  const float* Wo = (const float*)d_in[4];
  const float* bo = (const float*)d_in[5];
  const float* Wu = (const float*)d_in[6];
  const float* bu = (const float*)d_in[7];
  // d_in[8]=Wf, d_in[9]=bf_b, d_in[13]=Uf: dead in the reference (fc_sum bug)
  const float* Ui = (const float*)d_in[10];
  const float* Uo = (const float*)d_in[11];
  const float* Uu = (const float*)d_in[12];

  float* out = (float*)d_out;
  float* hf = out + (size_t)BB * MM;  // memory[:, :, :M] region, [T][B][M]

  // ws layout identical to R6/R7:
  int* cidx = (int*)d_ws;                    // 262144 ints
  int* root = cidx + (size_t)TT * BB * BFN;  // 512
  int* order = root + BB;                    // 256
  int* levelStart = order + TT;              // 8
  unsigned short* wb = (unsigned short*)((char*)d_ws + 1051712);   // 491520 sh
  unsigned short* xb = (unsigned short*)((char*)d_ws + 2034752);   // 16.7M sh
  unsigned short* hb = (unsigned short*)((char*)d_ws + 35589184);  // 33.5M sh
  unsigned short* zb = (unsigned short*)((char*)d_ws + 102698048); // 512 sh

  prep_sim<<<BB / 32, 32, 0, stream>>>(ar, cidx, root);
  prep_levels<<<1, 256, 0, stream>>>(cidx, order, levelStart);
  conv_all<<<8433, 256, 0, stream>>>(x, Wi, Wo, Wu, Ui, Uo, Uu, wb, xb, zb);
  for (int lev = 0; lev < NLEVEL_LAUNCH; lev++) {
    level_mfma<<<4096, 256, 0, stream>>>(xb, hf, hb, bi, bo, bu, wb, cidx,
                                         order, levelStart, zb, lev);
  }
  root_gather<<<(BB * MM) / 256, 256, 0, stream>>>(hf, root, out);
}